// Round 10
// baseline (284.760 us; speedup 1.0000x reference)
//
#include <hip/hip_runtime.h>
#include <stdint.h>
#include <math.h>

// ---------------------------------------------------------------------------
// DepthPriorLoss — 8 dispatches, no fences, no in-dispatch winner tails.
// Round-9 lesson: a single-block list-select tail costs ~60us regardless of
// load flavor (serial latency + clustered-bin LDS-atomic serialization).
// Fix: run the select REDUNDANTLY PER BLOCK at the head of the next kernel
// (private LDS hists -> fully parallel across blocks), and make each select
// fast via 8x-batched loads (ILP) + ballot-based wave-aggregated histogram
// updates (one atomicAdd per distinct bin per wave instead of per element).
// Cross-dispatch data: plain stores + dispatch boundary (proven rounds 1-7).
// All value-visible math identical to round-1 -> bit-exact outputs.
// ---------------------------------------------------------------------------

#define NT 256
#define GA 128    // hist1 + valid count (few blocks: flush-atomic contention)
#define GB 512    // bins1 + pairs/subs + collect1
#define GC 128    // (redundant med select) + hist2
#define GD 512    // bins2 + collect2
#define GE 256    // (redundant dyn select) + scoring
#define GF 1024   // argmax + final elemwise
#define LCAP 262144u

// word offsets in WS
enum : uint32_t {
  W_CNT  = 0,          // [4] list counters A1,B1,A2,B2
  W_LOSS = 4,          // [2] double (byte 16, 8-aligned)
  W_N    = 6,
  W_MED  = 7,
  W_SB1  = 8,          // binA1, rkA1, binB1, rkB1
  W_SB2  = 12,
  W_COUNTS = 20,       // int[1000] (atomic-accumulated -> must be zeroed)
  W_G1   = 1024,       // uint32[16384]
  W_G2   = 17408,      // uint32[16384]
  W_ZEND = 33792,      // zero everything below this
  W_PERC = 33792,      // uint32[GA] per-block valid counts (NOT zeroed)
  W_SCALES = 34816,    // float[1000]
  W_SHIFTS = 35816,    // float[1000]
  W_XSUB = 36816,      // float[50000]
  W_YSUB = 86816,      // float[50000]
  W_LA1  = 136832,     // uint32[LCAP] x 4
  W_LB1  = W_LA1 + LCAP,
  W_LA2  = W_LB1 + LCAP,
  W_LB2  = W_LA2 + LCAP
};

// ---------------- threefry2x32 (JAX-exact, partitionable mode) -------------
__device__ __forceinline__ uint32_t rotl32(uint32_t v, int d) {
  return (v << d) | (v >> (32 - d));
}
__device__ __forceinline__ void tf2x32(uint32_t k0, uint32_t k1,
                                       uint32_t c0, uint32_t c1,
                                       uint32_t& o0, uint32_t& o1) {
  uint32_t ks2 = k0 ^ k1 ^ 0x1BD11BDAu;
  uint32_t x0 = c0 + k0;
  uint32_t x1 = c1 + k1;
#define TFR(r) { x0 += x1; x1 = rotl32(x1, r); x1 ^= x0; }
  TFR(13) TFR(15) TFR(26) TFR(6)
  x0 += k1;  x1 += ks2 + 1u;
  TFR(17) TFR(29) TFR(16) TFR(24)
  x0 += ks2; x1 += k0 + 2u;
  TFR(13) TFR(15) TFR(26) TFR(6)
  x0 += k0;  x1 += k1 + 3u;
  TFR(17) TFR(29) TFR(16) TFR(24)
  x0 += k1;  x1 += ks2 + 4u;
  TFR(13) TFR(15) TFR(26) TFR(6)
  x0 += ks2; x1 += k0 + 5u;
#undef TFR
  o0 = x0; o1 = x1;
}
struct Keys { uint32_t hp0, hp1, lp0, lp1, hs0, hs1, ls0, ls1; };
__device__ __forceinline__ Keys derive_keys() {
  Keys K; uint32_t p0, p1, q0, q1;
  tf2x32(0u, 42u, 0u, 0u, p0, p1);
  tf2x32(0u, 42u, 0u, 1u, q0, q1);
  tf2x32(p0, p1, 0u, 0u, K.hp0, K.hp1);
  tf2x32(p0, p1, 0u, 1u, K.lp0, K.lp1);
  tf2x32(q0, q1, 0u, 0u, K.hs0, K.hs1);
  tf2x32(q0, q1, 0u, 1u, K.ls0, K.ls1);
  return K;
}
__device__ __forceinline__ uint32_t bits32(uint32_t k0, uint32_t k1, uint32_t e) {
  uint32_t a, b; tf2x32(k0, k1, 0u, e, a, b); return a ^ b;
}
__device__ __forceinline__ uint32_t ri_offset(uint32_t hi, uint32_t lo, uint32_t span) {
  uint32_t m = 65536u % span;
  m = (m * m) % span;
  uint32_t off = (hi % span) * m + (lo % span);
  return off % span;
}

// ---------------- order-preserving float<->uint ----------------------------
__device__ __forceinline__ uint32_t f2u(float f) {
  uint32_t u = __float_as_uint(f);
  return (u & 0x80000000u) ? ~u : (u | 0x80000000u);
}
__device__ __forceinline__ float u2f(uint32_t u) {
  uint32_t v = (u & 0x80000000u) ? (u & 0x7FFFFFFFu) : ~u;
  return __uint_as_float(v);
}
__device__ __forceinline__ uint32_t yval_u(float dv, float& y, bool& m) {
  y = __fdiv_rn(1.0f, __fadd_rn(dv, 1e-6f));
  m = (dv > 0.1f) && (dv < 100.0f) && isfinite(dv);
  return m ? f2u(y) : 0xFFFFFFFFu;
}
__device__ __forceinline__ uint32_t m2w(uint32_t u, float med) {
  return (u != 0xFFFFFFFFu) ? f2u(fabsf(__fsub_rn(u2f(u), med))) : 0xFFFFFFFFu;
}

// ---------------- block reduction / scan (256 threads) ---------------------
__device__ __forceinline__ uint32_t block_sum_u32(uint32_t v, uint32_t* wl) {
  const int lane = threadIdx.x & 63, wid = threadIdx.x >> 6;
  for (int off = 32; off > 0; off >>= 1) v += __shfl_down(v, off);
  __syncthreads();
  if (lane == 0) wl[wid] = v;
  __syncthreads();
  return wl[0] + wl[1] + wl[2] + wl[3];
}
__device__ __forceinline__ uint32_t scan_excl(uint32_t local, uint32_t* wl) {
  const int lane = threadIdx.x & 63, wid = threadIdx.x >> 6;
  __syncthreads();
  uint32_t v = local;
#pragma unroll
  for (int off = 1; off < 64; off <<= 1) {
    uint32_t o = __shfl_up(v, off);
    if (lane >= off) v += o;
  }
  if (lane == 63) wl[wid] = v;
  __syncthreads();
  uint32_t base = 0;
  for (int w = 0; w < 4; w++) if (w < wid) base += wl[w];
  return base + v - local;
}

// dual-rank select over a 16384-bin global hist (redundant per block)
__device__ void g_select2(const uint32_t* __restrict__ G, uint32_t rkA, uint32_t rkB,
                          uint32_t* wl, uint32_t* bc4) {
  const int tid = threadIdx.x;
  if (tid < 4) bc4[tid] = 0u;
  __syncthreads();
  uint32_t local = 0;
  for (int k = 0; k < 64; k++) local += G[tid * 64 + k];
  uint32_t excl = scan_excl(local, wl);
  for (int s = 0; s < 2; s++) {
    uint32_t rk = s ? rkB : rkA;
    if (local > 0 && rk >= excl && rk < excl + local) {
      uint32_t c = excl;
      for (int k = 0; k < 64; k++) {
        uint32_t v = G[tid * 64 + k];
        if (rk < c + v) { bc4[2 * s] = (uint32_t)(tid * 64 + k); bc4[2 * s + 1] = rk - c; break; }
        c += v;
      }
    }
  }
  __syncthreads();
}

// wave-aggregated LDS histogram add: one atomicAdd per distinct bin per wave
template <int BITS>
__device__ __forceinline__ void wave_hist_add(uint32_t* hist, uint32_t bin, bool part) {
  const int lane = threadIdx.x & 63;
  unsigned long long act = __ballot(part ? 1 : 0);
  unsigned long long m = act;
#pragma unroll
  for (int b = 0; b < BITS; b++) {
    bool bit = part && ((bin >> b) & 1u);
    unsigned long long vote = __ballot(bit ? 1 : 0);
    m &= ((bin >> b) & 1u) ? vote : ~vote;
  }
  if (part) {
    int leader = __ffsll(m) - 1;
    if (lane == leader) atomicAdd(&hist[bin], (uint32_t)__popcll(m));
  }
}

// exact rank-rk element of a coarse-bin list (per-block private LDS, runs
// redundantly in every block of the calling kernel — fully parallel).
// 8x-batched loads for ILP; wave-aggregated hist updates (no clustered-bin
// LDS serialization). value = ((16384+bin14)<<17) | (binA<<8) | binB
__device__ uint32_t select17i(const uint32_t* __restrict__ L, uint32_t cnt,
                              uint32_t rk, uint32_t bin14,
                              uint32_t* h512, uint32_t* h256,
                              uint32_t* wl, uint32_t* bc) {
  const int tid = threadIdx.x;
  __syncthreads();
  h512[2 * tid] = 0; h512[2 * tid + 1] = 0; h256[tid] = 0;
  if (tid < 2) bc[tid] = 0u;
  __syncthreads();
  // ---- pass 1: histogram bits [16:8]
  {
    uint32_t i = (uint32_t)tid;
    while (i + 7u * NT < cnt) {
      uint32_t v[8];
#pragma unroll
      for (int k = 0; k < 8; k++) v[k] = L[i + (uint32_t)k * NT];
#pragma unroll
      for (int k = 0; k < 8; k++)
        wave_hist_add<9>(h512, (v[k] >> 8) & 511u, true);
      i += 8u * NT;
    }
    for (; i < cnt; i += NT)
      wave_hist_add<9>(h512, (L[i] >> 8) & 511u, true);
  }
  __syncthreads();
  uint32_t a0 = h512[2 * tid], a1 = h512[2 * tid + 1];
  uint32_t local = a0 + a1;
  uint32_t excl = scan_excl(local, wl);
  if (local > 0 && rk >= excl && rk < excl + local) {
    if (rk < excl + a0) { bc[0] = (uint32_t)(2 * tid); bc[1] = rk - excl; }
    else { bc[0] = (uint32_t)(2 * tid + 1); bc[1] = rk - excl - a0; }
  }
  __syncthreads();
  uint32_t binA = bc[0], rk2 = bc[1];
  __syncthreads();
  // ---- pass 2: histogram bits [7:0] of elements matching binA
  {
    uint32_t i = (uint32_t)tid;
    while (i + 7u * NT < cnt) {
      uint32_t v[8];
#pragma unroll
      for (int k = 0; k < 8; k++) v[k] = L[i + (uint32_t)k * NT];
#pragma unroll
      for (int k = 0; k < 8; k++)
        wave_hist_add<8>(h256, v[k] & 255u, ((v[k] >> 8) & 511u) == binA);
      i += 8u * NT;
    }
    for (; i < cnt; i += NT) {
      uint32_t v = L[i];
      wave_hist_add<8>(h256, v & 255u, ((v >> 8) & 511u) == binA);
    }
  }
  __syncthreads();
  uint32_t l2 = h256[tid];
  uint32_t e2 = scan_excl(l2, wl);
  if (l2 > 0 && rk2 >= e2 && rk2 < e2 + l2) bc[0] = (uint32_t)tid;
  __syncthreads();
  uint32_t binB = bc[0];
  __syncthreads();
  return ((16384u + bin14) << 17) | (binA << 8) | binB;
}

// ---------------- kernels --------------------------------------------------
__global__ void k_zero(uint32_t* WS) {
  int i = blockIdx.x * blockDim.x + threadIdx.x;
  if (i < (int)W_ZEND) WS[i] = 0u;
}

// kA: stream dren -> valid count (W_PERC) + coarse hist G1 (packed-u16 LDS)
__global__ __launch_bounds__(NT) void kA(const float* __restrict__ dren,
                                         uint32_t* __restrict__ WS, int P) {
  const int tid = threadIdx.x, bid = blockIdx.x, gid = bid * NT + tid;
  __shared__ uint32_t lh[8192];
  __shared__ uint32_t wl[4];
  for (int i = tid; i < 8192; i += NT) lh[i] = 0u;
  __syncthreads();
  uint32_t cnt = 0;
  const float4* d4 = (const float4*)dren;
  const int P4 = P >> 2;
  for (int i = gid; i < P4; i += GA * NT) {
    float4 d = d4[i];
    float dc[4] = { d.x, d.y, d.z, d.w };
#pragma unroll
    for (int k = 0; k < 4; k++) {
      float y; bool m;
      uint32_t u = yval_u(dc[k], y, m);
      cnt += m ? 1u : 0u;
      uint32_t bin = (u >> 17) & 16383u;
      atomicAdd(&lh[bin >> 1], 1u << ((bin & 1u) << 4));
    }
  }
  for (int i = (P & ~3) + gid; i < P; i += GA * NT) {
    float y; bool m;
    uint32_t u = yval_u(dren[i], y, m);
    cnt += m ? 1u : 0u;
    uint32_t bin = (u >> 17) & 16383u;
    atomicAdd(&lh[bin >> 1], 1u << ((bin & 1u) << 4));
  }
  uint32_t btot = block_sum_u32(cnt, wl);
  if (tid == 0) WS[W_PERC + bid] = btot;
  __syncthreads();
  for (int w = tid; w < 8192; w += NT) {
    uint32_t pv = lh[w];
    if (pv) {
      uint32_t lo = pv & 0xFFFFu, hi = pv >> 16;
      if (lo) atomicAdd(&WS[W_G1 + 2 * w], lo);
      if (hi) atomicAdd(&WS[W_G1 + 2 * w + 1], hi);
    }
  }
}

// kB: redundant n + bins1 (-> W_N, W_SB1); pairs + subs; collect lists1
__global__ __launch_bounds__(NT) void kB(const float* __restrict__ dren,
                                         const float* __restrict__ dpri,
                                         uint32_t* __restrict__ WS, int P) {
  const int tid = threadIdx.x, bid = blockIdx.x, gid = bid * NT + tid;
  __shared__ uint32_t bufA[4096], bufB[4096];
  __shared__ uint32_t cA, cB, baseA, baseB;
  __shared__ uint32_t wl[4], bc4[4];
  // redundant n: exactly GA per-block counts exist (rest is poison!)
  uint32_t local = (tid < GA) ? WS[W_PERC + tid] : 0u;
  const uint32_t n = block_sum_u32(local, wl);
  const uint32_t nn = n ? n : 1u;
  g_select2(WS + W_G1, (nn - 1u) >> 1, nn >> 1, wl, bc4);
  const uint32_t binA1 = bc4[0], binB1 = bc4[2];
  const bool dv1 = (binA1 != binB1);
  if (tid == 0) {   // identical-value stores from every block: benign race
    WS[W_N] = n;
    WS[W_SB1 + 0] = bc4[0]; WS[W_SB1 + 1] = bc4[1];
    WS[W_SB1 + 2] = bc4[2]; WS[W_SB1 + 3] = bc4[3];
    cA = 0; cB = 0;
  }
  __syncthreads();
  // pairs + subs
  {
    uint32_t span = n ? n : 1u;
    if (gid < 1000) {
      Keys K = derive_keys();
      uint32_t hi0 = bits32(K.hp0, K.hp1, (uint32_t)(2 * gid));
      uint32_t lo0 = bits32(K.lp0, K.lp1, (uint32_t)(2 * gid));
      uint32_t hi1 = bits32(K.hp0, K.hp1, (uint32_t)(2 * gid + 1));
      uint32_t lo1 = bits32(K.lp0, K.lp1, (uint32_t)(2 * gid + 1));
      uint32_t i0 = ri_offset(hi0, lo0, span);
      uint32_t i1 = ri_offset(hi1, lo1, span);
      float x1v = dpri[i0], x2v = dpri[i1];
      float y1v = __fdiv_rn(1.0f, __fadd_rn(dren[i0], 1e-6f));
      float y2v = __fdiv_rn(1.0f, __fadd_rn(dren[i1], 1e-6f));
      float sc = __fdiv_rn(__fsub_rn(y2v, y1v),
                           __fadd_rn(__fsub_rn(x2v, x1v), 1e-8f));
      ((float*)WS)[W_SCALES + gid] = sc;
      ((float*)WS)[W_SHIFTS + gid] = __fsub_rn(y1v, __fmul_rn(sc, x1v));
    }
    if (gid < 50000) {
      Keys K = derive_keys();
      uint32_t hi = bits32(K.hs0, K.hs1, (uint32_t)gid);
      uint32_t lo = bits32(K.ls0, K.ls1, (uint32_t)gid);
      uint32_t idx = ri_offset(hi, lo, span);
      ((float*)WS)[W_XSUB + gid] = dpri[idx];
      ((float*)WS)[W_YSUB + gid] = __fdiv_rn(1.0f, __fadd_rn(dren[idx], 1e-6f));
    }
  }
  // collect coarse-bin elements (LDS staged, one global atomicAdd per list)
  const float4* d4 = (const float4*)dren;
  const int P4 = P >> 2;
  for (int i = gid; i < P4; i += GB * NT) {
    float4 d = d4[i];
    float dc[4] = { d.x, d.y, d.z, d.w };
#pragma unroll
    for (int k = 0; k < 4; k++) {
      float y; bool m;
      uint32_t u = yval_u(dc[k], y, m);
      uint32_t b = (u >> 17) & 16383u;
      if (b == binA1) { uint32_t j = atomicAdd(&cA, 1u); if (j < 4096u) bufA[j] = u; }
      else if (dv1 && b == binB1) { uint32_t j = atomicAdd(&cB, 1u); if (j < 4096u) bufB[j] = u; }
    }
  }
  for (int i = (P & ~3) + gid; i < P; i += GB * NT) {
    float y; bool m;
    uint32_t u = yval_u(dren[i], y, m);
    uint32_t b = (u >> 17) & 16383u;
    if (b == binA1) { uint32_t j = atomicAdd(&cA, 1u); if (j < 4096u) bufA[j] = u; }
    else if (dv1 && b == binB1) { uint32_t j = atomicAdd(&cB, 1u); if (j < 4096u) bufB[j] = u; }
  }
  __syncthreads();
  if (tid == 0) {
    uint32_t a = cA > 4096u ? 4096u : cA;
    uint32_t b = cB > 4096u ? 4096u : cB;
    cA = a; cB = b;
    baseA = a ? atomicAdd(&WS[W_CNT + 0], a) : 0u;
    baseB = b ? atomicAdd(&WS[W_CNT + 1], b) : 0u;
  }
  __syncthreads();
  for (uint32_t k = tid; k < cA; k += NT)
    if (baseA + k < LCAP) WS[W_LA1 + baseA + k] = bufA[k];
  for (uint32_t k = tid; k < cB; k += NT)
    if (baseB + k < LCAP) WS[W_LB1 + baseB + k] = bufB[k];
}

// kC: redundant-per-block exact median(y) (parallel selects) -> W_MED;
// then stream hist of |y - med| -> G2
__global__ __launch_bounds__(NT) void kC(const float* __restrict__ dren,
                                         uint32_t* __restrict__ WS, int P) {
  const int tid = threadIdx.x, bid = blockIdx.x, gid = bid * NT + tid;
  __shared__ uint32_t lh[8192];
  __shared__ uint32_t h512[512], h256[256];
  __shared__ uint32_t wl[4], bc[2];
  const uint32_t binA1 = WS[W_SB1 + 0], rkA1 = WS[W_SB1 + 1];
  const uint32_t binB1 = WS[W_SB1 + 2], rkB1 = WS[W_SB1 + 3];
  const bool dv1 = (binA1 != binB1);
  uint32_t cA1 = WS[W_CNT + 0]; if (cA1 > LCAP) cA1 = LCAP;
  uint32_t vA = select17i(WS + W_LA1, cA1, rkA1, binA1, h512, h256, wl, bc);
  uint32_t vB;
  if (dv1) {
    uint32_t cB1 = WS[W_CNT + 1]; if (cB1 > LCAP) cB1 = LCAP;
    vB = select17i(WS + W_LB1, cB1, rkB1, binB1, h512, h256, wl, bc);
  } else {
    vB = select17i(WS + W_LA1, cA1, rkB1, binA1, h512, h256, wl, bc);
  }
  const float med = __fmul_rn(__fadd_rn(u2f(vA), u2f(vB)), 0.5f);
  if (tid == 0) ((float*)WS)[W_MED] = med;   // identical across blocks
  __syncthreads();
  for (int i = tid; i < 8192; i += NT) lh[i] = 0u;
  __syncthreads();
  const float4* d4 = (const float4*)dren;
  const int P4 = P >> 2;
  for (int i = gid; i < P4; i += GC * NT) {
    float4 d = d4[i];
    float dc[4] = { d.x, d.y, d.z, d.w };
#pragma unroll
    for (int k = 0; k < 4; k++) {
      float y; bool m;
      uint32_t w = m2w(yval_u(dc[k], y, m), med);
      uint32_t bin = (w >> 17) & 16383u;
      atomicAdd(&lh[bin >> 1], 1u << ((bin & 1u) << 4));
    }
  }
  for (int i = (P & ~3) + gid; i < P; i += GC * NT) {
    float y; bool m;
    uint32_t w = m2w(yval_u(dren[i], y, m), med);
    uint32_t bin = (w >> 17) & 16383u;
    atomicAdd(&lh[bin >> 1], 1u << ((bin & 1u) << 4));
  }
  __syncthreads();
  for (int w = tid; w < 8192; w += NT) {
    uint32_t pv = lh[w];
    if (pv) {
      uint32_t lo = pv & 0xFFFFu, hi = pv >> 16;
      if (lo) atomicAdd(&WS[W_G2 + 2 * w], lo);
      if (hi) atomicAdd(&WS[W_G2 + 2 * w + 1], hi);
    }
  }
}

// kD: redundant bins2 from G2 (-> W_SB2); collect median-2 lists
__global__ __launch_bounds__(NT) void kD(const float* __restrict__ dren,
                                         uint32_t* __restrict__ WS, int P) {
  const int tid = threadIdx.x, bid = blockIdx.x, gid = bid * NT + tid;
  __shared__ uint32_t bufA[4096], bufB[4096];
  __shared__ uint32_t cA, cB, baseA, baseB;
  __shared__ uint32_t wl[4], bc4[4];
  const float med = ((const float*)WS)[W_MED];
  const uint32_t n = WS[W_N];
  const uint32_t nn = n ? n : 1u;
  g_select2(WS + W_G2, (nn - 1u) >> 1, nn >> 1, wl, bc4);
  const uint32_t binA2 = bc4[0], binB2 = bc4[2];
  const bool dv2 = (binA2 != binB2);
  if (tid == 0) {
    WS[W_SB2 + 0] = bc4[0]; WS[W_SB2 + 1] = bc4[1];
    WS[W_SB2 + 2] = bc4[2]; WS[W_SB2 + 3] = bc4[3];
    cA = 0; cB = 0;
  }
  __syncthreads();
  const float4* d4 = (const float4*)dren;
  const int P4 = P >> 2;
  for (int i = gid; i < P4; i += GD * NT) {
    float4 d = d4[i];
    float dc[4] = { d.x, d.y, d.z, d.w };
#pragma unroll
    for (int k = 0; k < 4; k++) {
      float y; bool m;
      uint32_t w = m2w(yval_u(dc[k], y, m), med);
      uint32_t b = (w >> 17) & 16383u;
      if (b == binA2) { uint32_t j = atomicAdd(&cA, 1u); if (j < 4096u) bufA[j] = w; }
      else if (dv2 && b == binB2) { uint32_t j = atomicAdd(&cB, 1u); if (j < 4096u) bufB[j] = w; }
    }
  }
  for (int i = (P & ~3) + gid; i < P; i += GD * NT) {
    float y; bool m;
    uint32_t w = m2w(yval_u(dren[i], y, m), med);
    uint32_t b = (w >> 17) & 16383u;
    if (b == binA2) { uint32_t j = atomicAdd(&cA, 1u); if (j < 4096u) bufA[j] = w; }
    else if (dv2 && b == binB2) { uint32_t j = atomicAdd(&cB, 1u); if (j < 4096u) bufB[j] = w; }
  }
  __syncthreads();
  if (tid == 0) {
    uint32_t a = cA > 4096u ? 4096u : cA;
    uint32_t b = cB > 4096u ? 4096u : cB;
    cA = a; cB = b;
    baseA = a ? atomicAdd(&WS[W_CNT + 2], a) : 0u;
    baseB = b ? atomicAdd(&WS[W_CNT + 3], b) : 0u;
  }
  __syncthreads();
  for (uint32_t k = tid; k < cA; k += NT)
    if (baseA + k < LCAP) WS[W_LA2 + baseA + k] = bufA[k];
  for (uint32_t k = tid; k < cB; k += NT)
    if (baseB + k < LCAP) WS[W_LB2 + baseB + k] = bufB[k];
}

// kE: redundant-per-block dyn (parallel selects); element-sliced scoring
__global__ __launch_bounds__(NT) void kE(uint32_t* __restrict__ WS) {
  const int tid = threadIdx.x, bid = blockIdx.x;
  __shared__ uint32_t h512[512], h256[256];
  __shared__ uint32_t wl[4], bc[2];
  __shared__ float lx[200], ly[200];
  const uint32_t binA2 = WS[W_SB2 + 0], rkA2 = WS[W_SB2 + 1];
  const uint32_t binB2 = WS[W_SB2 + 2], rkB2 = WS[W_SB2 + 3];
  const bool dv2 = (binA2 != binB2);
  uint32_t cA2 = WS[W_CNT + 2]; if (cA2 > LCAP) cA2 = LCAP;
  uint32_t wA = select17i(WS + W_LA2, cA2, rkA2, binA2, h512, h256, wl, bc);
  uint32_t wB;
  if (dv2) {
    uint32_t cB2 = WS[W_CNT + 3]; if (cB2 > LCAP) cB2 = LCAP;
    wB = select17i(WS + W_LB2, cB2, rkB2, binB2, h512, h256, wl, bc);
  } else {
    wB = select17i(WS + W_LA2, cA2, rkB2, binA2, h512, h256, wl, bc);
  }
  float mad = __fmul_rn(__fadd_rn(u2f(wA), u2f(wB)), 0.5f);
  float dyn = __fmul_rn(mad, 0.5f);
  if (dyn < 1e-5f) dyn = 0.01f;   // THRESH
  // scoring: block owns ~196 (x,y) in LDS, thread owns 4 candidates
  const int e0 = (bid * 50000) / GE, e1 = ((bid + 1) * 50000) / GE;
  const int cnt = e1 - e0;
  const float* x_sub = (const float*)WS + W_XSUB;
  const float* y_sub = (const float*)WS + W_YSUB;
  if (tid < cnt) { lx[tid] = x_sub[e0 + tid]; ly[tid] = y_sub[e0 + tid]; }
  __syncthreads();
  const float* scales = (const float*)WS + W_SCALES;
  const float* shifts = (const float*)WS + W_SHIFTS;
  float ss[4], tt[4]; int c[4];
#pragma unroll
  for (int j = 0; j < 4; j++) {
    int cand = tid + 256 * j;
    ss[j] = (cand < 1000) ? scales[cand] : 0.0f;
    tt[j] = (cand < 1000) ? shifts[cand] : 0.0f;
    c[j] = 0;
  }
  for (int e = 0; e < cnt; e++) {
    float xe = lx[e], ye = ly[e];   // LDS broadcast: conflict-free
#pragma unroll
    for (int j = 0; j < 4; j++) {
      float r = fabsf(__fsub_rn(__fadd_rn(__fmul_rn(ss[j], xe), tt[j]), ye));
      c[j] += (r < dyn) ? 1 : 0;
    }
  }
  int* counts = (int*)WS + W_COUNTS;
#pragma unroll
  for (int j = 0; j < 4; j++) {
    int cand = tid + 256 * j;
    if (cand < 1000 && c[j] > 0) atomicAdd(&counts[cand], c[j]);
  }
}

// kF: redundant argmax -> s,t; final elemwise; per-block loss atomicAdd
__global__ __launch_bounds__(NT) void kF(const float* __restrict__ dren,
                                         const float* __restrict__ dpri,
                                         float* __restrict__ out,
                                         uint32_t* __restrict__ WS, int P) {
  const int tid = threadIdx.x, bid = blockIdx.x, gid = bid * NT + tid;
  const int lane = tid & 63, wid = tid >> 6;
  __shared__ int ired[4], iidx[4];
  __shared__ float fbcast[2];
  __shared__ double dred[4];
  {
    const int* counts = (const int*)WS + W_COUNTS;
    const float* scales = (const float*)WS + W_SCALES;
    const float* shifts = (const float*)WS + W_SHIFTS;
    int bcn = -2, bix = 0x7FFFFFFF;
    for (int j = tid; j < 1000; j += NT) {
      int cc = counts[j];
      if (!(scales[j] > 0.0f)) cc = -1;
      if (cc > bcn) { bcn = cc; bix = j; }
    }
    for (int off = 32; off > 0; off >>= 1) {
      int oc = __shfl_down(bcn, off), oi = __shfl_down(bix, off);
      if (oc > bcn || (oc == bcn && oi < bix)) { bcn = oc; bix = oi; }
    }
    if (lane == 0) { ired[wid] = bcn; iidx[wid] = bix; }
    __syncthreads();
    if (tid == 0) {
      for (int w = 1; w < 4; w++) {
        if (ired[w] > ired[0] || (ired[w] == ired[0] && iidx[w] < iidx[0])) {
          ired[0] = ired[w]; iidx[0] = iidx[w];
        }
      }
      bool valid = ired[0] >= 0;
      float s = valid ? scales[iidx[0]] : 1.0f;
      float t = valid ? shifts[iidx[0]] : 0.0f;
      uint32_t n = WS[W_N];
      if (n < 10u) { s = 1.0f; t = 0.0f; }
      fbcast[0] = s; fbcast[1] = t;
    }
    __syncthreads();
  }
  const float s = fbcast[0], t = fbcast[1];
  float* out_y = out + 1;
  float* out_depth = out + 1 + P;
  double acc = 0.0;
  const float4* d4 = (const float4*)dren;
  const float4* p4 = (const float4*)dpri;
  const int P4 = P >> 2;
  for (int i = gid; i < P4; i += GF * NT) {
    float4 d = d4[i], p = p4[i];
    float dc[4] = { d.x, d.y, d.z, d.w };
    float pc[4] = { p.x, p.y, p.z, p.w };
#pragma unroll
    for (int k = 0; k < 4; k++) {
      float yv = __fdiv_rn(1.0f, __fadd_rn(dc[k], 1e-6f));
      out_y[4 * i + k] = yv;
      float al = __fadd_rn(__fmul_rn(s, pc[k]), t);
      out_depth[4 * i + k] = __fdiv_rn(1.0f, fmaxf(al, 1e-4f));
      bool m = (dc[k] > 0.1f) && (dc[k] < 100.0f) && isfinite(dc[k]);
      if (m) acc += (double)fabsf(__fsub_rn(al, yv));
    }
  }
  for (int i = (P & ~3) + gid; i < P; i += GF * NT) {
    float dv = dren[i];
    float yv = __fdiv_rn(1.0f, __fadd_rn(dv, 1e-6f));
    out_y[i] = yv;
    float al = __fadd_rn(__fmul_rn(s, dpri[i]), t);
    out_depth[i] = __fdiv_rn(1.0f, fmaxf(al, 1e-4f));
    bool m = (dv > 0.1f) && (dv < 100.0f) && isfinite(dv);
    if (m) acc += (double)fabsf(__fsub_rn(al, yv));
  }
  for (int off = 32; off > 0; off >>= 1) acc += __shfl_down(acc, off);
  __syncthreads();
  if (lane == 0) dred[wid] = acc;
  __syncthreads();
  if (tid == 0)
    atomicAdd((double*)(WS + W_LOSS), dred[0] + dred[1] + dred[2] + dred[3]);
}

// kG: final loss scalar
__global__ void kG(const uint32_t* __restrict__ WS, float* __restrict__ out) {
  if (threadIdx.x == 0 && blockIdx.x == 0) {
    double total = *((const double*)(WS + W_LOSS));
    uint32_t n = WS[W_N];
    uint32_t nd = n ? n : 1u;
    float l1 = __fdiv_rn((float)total, (float)nd);
    out[0] = (n < 100u) ? 0.0f : __fmul_rn(0.5f, l1);
  }
}

// ---------------------------------------------------------------------------
extern "C" void kernel_launch(void* const* d_in, const int* in_sizes, int n_in,
                              void* d_out, int out_size, void* d_ws, size_t ws_size,
                              hipStream_t stream) {
  const float* d_ren = (const float*)d_in[0];
  const float* d_pri = (const float*)d_in[1];
  float* out = (float*)d_out;
  uint32_t* WS = (uint32_t*)d_ws;
  int P = in_sizes[0];

  k_zero<<<(W_ZEND + NT - 1) / NT, NT, 0, stream>>>(WS);
  kA<<<GA, NT, 0, stream>>>(d_ren, WS, P);
  kB<<<GB, NT, 0, stream>>>(d_ren, d_pri, WS, P);
  kC<<<GC, NT, 0, stream>>>(d_ren, WS, P);
  kD<<<GD, NT, 0, stream>>>(d_ren, WS, P);
  kE<<<GE, NT, 0, stream>>>(WS);
  kF<<<GF, NT, 0, stream>>>(d_ren, d_pri, out, WS, P);
  kG<<<1, 64, 0, stream>>>(WS, out);
}

// Round 11
// 197.526 us; speedup vs baseline: 1.4416x; 1.4416x over previous
//
#include <hip/hip_runtime.h>
#include <stdint.h>
#include <math.h>

// ---------------------------------------------------------------------------
// DepthPriorLoss — 10 dispatches (round-7 topology, proven best at 226us),
// with the two list-select kernels (kMed/kDyn) made ~10x cheaper:
// kB/kD now ALSO build a 2nd-level 2048-bin histogram (value bits [16:6])
// of the coarse-bin elements while collecting the lists, so kMed/kDyn do
// no list histogramming at all: one hist-select + one compare-only batched
// list pass collecting ~7 sub-bin elements + a 64-bin select of bits [5:0].
// Round 8-10 lessons: no fences, no winner tails, no wide redundant selects.
// All value-visible math identical to the passing round-1 code -> bit-exact.
// ---------------------------------------------------------------------------

#define NT 256
#define GA 128    // hist1 + valid count (few blocks: flush-atomic contention)
#define GB 512    // bins1 + pairs/subs + collect1 + subhist1
#define GC 128    // hist2
#define GD 512    // bins2 + collect2 + subhist2
#define GE 256    // scoring: element-sliced, all candidates per block
#define GF 1024   // argmax + final elemwise
#define LCAP 262144u

// word offsets in WS
enum : uint32_t {
  W_CNT  = 0,          // [4] list counters A1,B1,A2,B2
  W_LOSS = 4,          // [2] double (byte 16, 8-aligned)
  W_N    = 6,
  W_VA   = 7, W_VB = 8,   // selected u32 values, median 1
  W_WA   = 9, W_WB = 10,  // selected u32 values, median 2
  W_SB1  = 12,         // binA1, rkA1, binB1, rkB1
  W_SB2  = 16,
  W_COUNTS = 20,       // int[1000] (atomic-accumulated -> must be zeroed)
  W_G1   = 1024,       // uint32[16384] coarse hist (bits [30:17])
  W_G2   = 17408,      // uint32[16384]
  W_H1A  = 33792,      // uint32[2048] sub-hist (bits [16:6]) list A1
  W_H1B  = 35840,      // uint32[2048] list B1
  W_H2A  = 37888,      // uint32[2048] list A2
  W_H2B  = 39936,      // uint32[2048] list B2
  W_ZEND = 41984,      // zero everything below this
  W_PERC = 41984,      // uint32[GA] per-block valid counts (NOT zeroed)
  W_SCALES = 43008,    // float[1000]
  W_SHIFTS = 44008,    // float[1000]
  W_XSUB = 45008,      // float[50000]
  W_YSUB = 95008,      // float[50000]
  W_LA1  = 145024,     // uint32[LCAP] x 4
  W_LB1  = W_LA1 + LCAP,
  W_LA2  = W_LB1 + LCAP,
  W_LB2  = W_LA2 + LCAP
};

// ---------------- threefry2x32 (JAX-exact, partitionable mode) -------------
__device__ __forceinline__ uint32_t rotl32(uint32_t v, int d) {
  return (v << d) | (v >> (32 - d));
}
__device__ __forceinline__ void tf2x32(uint32_t k0, uint32_t k1,
                                       uint32_t c0, uint32_t c1,
                                       uint32_t& o0, uint32_t& o1) {
  uint32_t ks2 = k0 ^ k1 ^ 0x1BD11BDAu;
  uint32_t x0 = c0 + k0;
  uint32_t x1 = c1 + k1;
#define TFR(r) { x0 += x1; x1 = rotl32(x1, r); x1 ^= x0; }
  TFR(13) TFR(15) TFR(26) TFR(6)
  x0 += k1;  x1 += ks2 + 1u;
  TFR(17) TFR(29) TFR(16) TFR(24)
  x0 += ks2; x1 += k0 + 2u;
  TFR(13) TFR(15) TFR(26) TFR(6)
  x0 += k0;  x1 += k1 + 3u;
  TFR(17) TFR(29) TFR(16) TFR(24)
  x0 += k1;  x1 += ks2 + 4u;
  TFR(13) TFR(15) TFR(26) TFR(6)
  x0 += ks2; x1 += k0 + 5u;
#undef TFR
  o0 = x0; o1 = x1;
}
struct Keys { uint32_t hp0, hp1, lp0, lp1, hs0, hs1, ls0, ls1; };
__device__ __forceinline__ Keys derive_keys() {
  Keys K; uint32_t p0, p1, q0, q1;
  tf2x32(0u, 42u, 0u, 0u, p0, p1);
  tf2x32(0u, 42u, 0u, 1u, q0, q1);
  tf2x32(p0, p1, 0u, 0u, K.hp0, K.hp1);
  tf2x32(p0, p1, 0u, 1u, K.lp0, K.lp1);
  tf2x32(q0, q1, 0u, 0u, K.hs0, K.hs1);
  tf2x32(q0, q1, 0u, 1u, K.ls0, K.ls1);
  return K;
}
__device__ __forceinline__ uint32_t bits32(uint32_t k0, uint32_t k1, uint32_t e) {
  uint32_t a, b; tf2x32(k0, k1, 0u, e, a, b); return a ^ b;
}
__device__ __forceinline__ uint32_t ri_offset(uint32_t hi, uint32_t lo, uint32_t span) {
  uint32_t m = 65536u % span;
  m = (m * m) % span;
  uint32_t off = (hi % span) * m + (lo % span);
  return off % span;
}

// ---------------- order-preserving float<->uint ----------------------------
__device__ __forceinline__ uint32_t f2u(float f) {
  uint32_t u = __float_as_uint(f);
  return (u & 0x80000000u) ? ~u : (u | 0x80000000u);
}
__device__ __forceinline__ float u2f(uint32_t u) {
  uint32_t v = (u & 0x80000000u) ? (u & 0x7FFFFFFFu) : ~u;
  return __uint_as_float(v);
}
__device__ __forceinline__ uint32_t yval_u(float dv, float& y, bool& m) {
  y = __fdiv_rn(1.0f, __fadd_rn(dv, 1e-6f));
  m = (dv > 0.1f) && (dv < 100.0f) && isfinite(dv);
  return m ? f2u(y) : 0xFFFFFFFFu;
}
__device__ __forceinline__ uint32_t m2w(uint32_t u, float med) {
  return (u != 0xFFFFFFFFu) ? f2u(fabsf(__fsub_rn(u2f(u), med))) : 0xFFFFFFFFu;
}
__device__ __forceinline__ float med_from(const uint32_t* WS) {
  return __fmul_rn(__fadd_rn(u2f(WS[W_VA]), u2f(WS[W_VB])), 0.5f);
}

// ---------------- block reduction / scan (256 threads) ---------------------
__device__ __forceinline__ uint32_t block_sum_u32(uint32_t v, uint32_t* wl) {
  const int lane = threadIdx.x & 63, wid = threadIdx.x >> 6;
  for (int off = 32; off > 0; off >>= 1) v += __shfl_down(v, off);
  __syncthreads();
  if (lane == 0) wl[wid] = v;
  __syncthreads();
  return wl[0] + wl[1] + wl[2] + wl[3];
}
__device__ __forceinline__ uint32_t scan_excl(uint32_t local, uint32_t* wl) {
  const int lane = threadIdx.x & 63, wid = threadIdx.x >> 6;
  __syncthreads();
  uint32_t v = local;
#pragma unroll
  for (int off = 1; off < 64; off <<= 1) {
    uint32_t o = __shfl_up(v, off);
    if (lane >= off) v += o;
  }
  if (lane == 63) wl[wid] = v;
  __syncthreads();
  uint32_t base = 0;
  for (int w = 0; w < 4; w++) if (w < wid) base += wl[w];
  return base + v - local;
}

// dual-rank select over a 16384-bin global hist (redundant per block)
__device__ void g_select2(const uint32_t* __restrict__ G, uint32_t rkA, uint32_t rkB,
                          uint32_t* wl, uint32_t* bc4) {
  const int tid = threadIdx.x;
  if (tid < 4) bc4[tid] = 0u;
  __syncthreads();
  uint32_t local = 0;
  for (int k = 0; k < 64; k++) local += G[tid * 64 + k];
  uint32_t excl = scan_excl(local, wl);
  for (int s = 0; s < 2; s++) {
    uint32_t rk = s ? rkB : rkA;
    if (local > 0 && rk >= excl && rk < excl + local) {
      uint32_t c = excl;
      for (int k = 0; k < 64; k++) {
        uint32_t v = G[tid * 64 + k];
        if (rk < c + v) { bc4[2 * s] = (uint32_t)(tid * 64 + k); bc4[2 * s + 1] = rk - c; break; }
        c += v;
      }
    }
  }
  __syncthreads();
}

// single-rank select over a 2048-bin global hist (8 bins/thread)
__device__ void h_select(const uint32_t* __restrict__ H, uint32_t rk,
                         uint32_t* wl, uint32_t* bc) {
  const int tid = threadIdx.x;
  if (tid < 2) bc[tid] = 0u;
  __syncthreads();
  uint32_t v8[8];
  uint32_t local = 0;
#pragma unroll
  for (int k = 0; k < 8; k++) { v8[k] = H[tid * 8 + k]; local += v8[k]; }
  uint32_t excl = scan_excl(local, wl);
  if (local > 0 && rk >= excl && rk < excl + local) {
    uint32_t c = excl;
#pragma unroll
    for (int k = 0; k < 8; k++) {
      if (rk < c + v8[k]) { bc[0] = (uint32_t)(tid * 8 + k); bc[1] = rk - c; break; }
      c += v8[k];
    }
  }
  __syncthreads();
}

// ---------------- kernels --------------------------------------------------
__global__ void k_zero(uint32_t* WS) {
  int i = blockIdx.x * blockDim.x + threadIdx.x;
  if (i < (int)W_ZEND) WS[i] = 0u;
}

// kA: stream dren -> valid count (W_PERC) + coarse hist G1 (packed-u16 LDS)
__global__ __launch_bounds__(NT) void kA(const float* __restrict__ dren,
                                         uint32_t* __restrict__ WS, int P) {
  const int tid = threadIdx.x, bid = blockIdx.x, gid = bid * NT + tid;
  __shared__ uint32_t lh[8192];
  __shared__ uint32_t wl[4];
  for (int i = tid; i < 8192; i += NT) lh[i] = 0u;
  __syncthreads();
  uint32_t cnt = 0;
  const float4* d4 = (const float4*)dren;
  const int P4 = P >> 2;
  for (int i = gid; i < P4; i += GA * NT) {
    float4 d = d4[i];
    float dc[4] = { d.x, d.y, d.z, d.w };
#pragma unroll
    for (int k = 0; k < 4; k++) {
      float y; bool m;
      uint32_t u = yval_u(dc[k], y, m);
      cnt += m ? 1u : 0u;
      uint32_t bin = (u >> 17) & 16383u;
      atomicAdd(&lh[bin >> 1], 1u << ((bin & 1u) << 4));
    }
  }
  for (int i = (P & ~3) + gid; i < P; i += GA * NT) {
    float y; bool m;
    uint32_t u = yval_u(dren[i], y, m);
    cnt += m ? 1u : 0u;
    uint32_t bin = (u >> 17) & 16383u;
    atomicAdd(&lh[bin >> 1], 1u << ((bin & 1u) << 4));
  }
  uint32_t btot = block_sum_u32(cnt, wl);
  if (tid == 0) WS[W_PERC + bid] = btot;
  __syncthreads();
  for (int w = tid; w < 8192; w += NT) {
    uint32_t pv = lh[w];
    if (pv) {
      uint32_t lo = pv & 0xFFFFu, hi = pv >> 16;
      if (lo) atomicAdd(&WS[W_G1 + 2 * w], lo);
      if (hi) atomicAdd(&WS[W_G1 + 2 * w + 1], hi);
    }
  }
}

// kB: redundant n + bins1 (-> W_N, W_SB1); pairs + subs; collect lists1 +
// sub-hists (bits [16:6]) of list elements -> W_H1A/W_H1B
__global__ __launch_bounds__(NT) void kB(const float* __restrict__ dren,
                                         const float* __restrict__ dpri,
                                         uint32_t* __restrict__ WS, int P) {
  const int tid = threadIdx.x, bid = blockIdx.x, gid = bid * NT + tid;
  __shared__ uint32_t bufA[4096], bufB[4096];
  __shared__ uint32_t h2A[2048], h2B[2048];
  __shared__ uint32_t cA, cB, baseA, baseB;
  __shared__ uint32_t wl[4], bc4[4];
  // redundant n: exactly GA per-block counts exist (rest is poison!)
  uint32_t local = (tid < GA) ? WS[W_PERC + tid] : 0u;
  const uint32_t n = block_sum_u32(local, wl);
  const uint32_t nn = n ? n : 1u;
  g_select2(WS + W_G1, (nn - 1u) >> 1, nn >> 1, wl, bc4);
  const uint32_t binA1 = bc4[0], binB1 = bc4[2];
  const bool dv1 = (binA1 != binB1);
  if (tid == 0) {   // identical-value stores from every block: benign race
    WS[W_N] = n;
    WS[W_SB1 + 0] = bc4[0]; WS[W_SB1 + 1] = bc4[1];
    WS[W_SB1 + 2] = bc4[2]; WS[W_SB1 + 3] = bc4[3];
    cA = 0; cB = 0;
  }
  for (int i = tid; i < 2048; i += NT) { h2A[i] = 0u; h2B[i] = 0u; }
  __syncthreads();
  // pairs + subs
  {
    uint32_t span = n ? n : 1u;
    if (gid < 1000) {
      Keys K = derive_keys();
      uint32_t hi0 = bits32(K.hp0, K.hp1, (uint32_t)(2 * gid));
      uint32_t lo0 = bits32(K.lp0, K.lp1, (uint32_t)(2 * gid));
      uint32_t hi1 = bits32(K.hp0, K.hp1, (uint32_t)(2 * gid + 1));
      uint32_t lo1 = bits32(K.lp0, K.lp1, (uint32_t)(2 * gid + 1));
      uint32_t i0 = ri_offset(hi0, lo0, span);
      uint32_t i1 = ri_offset(hi1, lo1, span);
      float x1v = dpri[i0], x2v = dpri[i1];
      float y1v = __fdiv_rn(1.0f, __fadd_rn(dren[i0], 1e-6f));
      float y2v = __fdiv_rn(1.0f, __fadd_rn(dren[i1], 1e-6f));
      float sc = __fdiv_rn(__fsub_rn(y2v, y1v),
                           __fadd_rn(__fsub_rn(x2v, x1v), 1e-8f));
      ((float*)WS)[W_SCALES + gid] = sc;
      ((float*)WS)[W_SHIFTS + gid] = __fsub_rn(y1v, __fmul_rn(sc, x1v));
    }
    if (gid < 50000) {
      Keys K = derive_keys();
      uint32_t hi = bits32(K.hs0, K.hs1, (uint32_t)gid);
      uint32_t lo = bits32(K.ls0, K.ls1, (uint32_t)gid);
      uint32_t idx = ri_offset(hi, lo, span);
      ((float*)WS)[W_XSUB + gid] = dpri[idx];
      ((float*)WS)[W_YSUB + gid] = __fdiv_rn(1.0f, __fadd_rn(dren[idx], 1e-6f));
    }
  }
  // collect coarse-bin elements + build sub-hist of bits [16:6]
  const float4* d4 = (const float4*)dren;
  const int P4 = P >> 2;
  for (int i = gid; i < P4; i += GB * NT) {
    float4 d = d4[i];
    float dc[4] = { d.x, d.y, d.z, d.w };
#pragma unroll
    for (int k = 0; k < 4; k++) {
      float y; bool m;
      uint32_t u = yval_u(dc[k], y, m);
      uint32_t b = (u >> 17) & 16383u;
      if (b == binA1) {
        uint32_t j = atomicAdd(&cA, 1u); if (j < 4096u) bufA[j] = u;
        atomicAdd(&h2A[(u >> 6) & 2047u], 1u);
      } else if (dv1 && b == binB1) {
        uint32_t j = atomicAdd(&cB, 1u); if (j < 4096u) bufB[j] = u;
        atomicAdd(&h2B[(u >> 6) & 2047u], 1u);
      }
    }
  }
  for (int i = (P & ~3) + gid; i < P; i += GB * NT) {
    float y; bool m;
    uint32_t u = yval_u(dren[i], y, m);
    uint32_t b = (u >> 17) & 16383u;
    if (b == binA1) {
      uint32_t j = atomicAdd(&cA, 1u); if (j < 4096u) bufA[j] = u;
      atomicAdd(&h2A[(u >> 6) & 2047u], 1u);
    } else if (dv1 && b == binB1) {
      uint32_t j = atomicAdd(&cB, 1u); if (j < 4096u) bufB[j] = u;
      atomicAdd(&h2B[(u >> 6) & 2047u], 1u);
    }
  }
  __syncthreads();
  if (tid == 0) {
    uint32_t a = cA > 4096u ? 4096u : cA;
    uint32_t b = cB > 4096u ? 4096u : cB;
    cA = a; cB = b;
    baseA = a ? atomicAdd(&WS[W_CNT + 0], a) : 0u;
    baseB = b ? atomicAdd(&WS[W_CNT + 1], b) : 0u;
  }
  __syncthreads();
  for (uint32_t k = tid; k < cA; k += NT)
    if (baseA + k < LCAP) WS[W_LA1 + baseA + k] = bufA[k];
  for (uint32_t k = tid; k < cB; k += NT)
    if (baseB + k < LCAP) WS[W_LB1 + baseB + k] = bufB[k];
  for (int w = tid; w < 2048; w += NT) {
    uint32_t a = h2A[w]; if (a) atomicAdd(&WS[W_H1A + w], a);
    uint32_t b = h2B[w]; if (b) atomicAdd(&WS[W_H1B + w], b);
  }
}

// kMed: 2 blocks; block b resolves rank b of median(y) -> W_VA / W_VB.
// Uses precomputed 2048-bin sub-hist (no list histogramming): hist select ->
// one compare-only batched list pass collecting the tiny sub-bin -> 64-bin
// select of bits [5:0].
__global__ __launch_bounds__(NT) void kMed(uint32_t* __restrict__ WS) {
  const int tid = threadIdx.x, bid = blockIdx.x;
  __shared__ uint32_t tiny[256];
  __shared__ uint32_t h64[64];
  __shared__ uint32_t wl[4], bc[2];
  __shared__ uint32_t tcnt;
  const uint32_t binA1 = WS[W_SB1 + 0], rkA1 = WS[W_SB1 + 1];
  const uint32_t binB1 = WS[W_SB1 + 2], rkB1 = WS[W_SB1 + 3];
  const bool dv1 = (binA1 != binB1);
  uint32_t coarse, rk; const uint32_t *L, *H; uint32_t cnt;
  if (bid == 0) {
    coarse = binA1; rk = rkA1; L = WS + W_LA1; H = WS + W_H1A;
    cnt = WS[W_CNT + 0];
  } else {
    coarse = dv1 ? binB1 : binA1; rk = rkB1;
    L = dv1 ? (WS + W_LB1) : (WS + W_LA1);
    H = dv1 ? (WS + W_H1B) : (WS + W_H1A);
    cnt = dv1 ? WS[W_CNT + 1] : WS[W_CNT + 0];
  }
  if (cnt > LCAP) cnt = LCAP;
  h_select(H, rk, wl, bc);
  const uint32_t bin11 = bc[0], rk2 = bc[1];
  if (tid == 0) tcnt = 0u;
  if (tid < 64) h64[tid] = 0u;
  if (tid < 2) { __syncthreads(); } else { __syncthreads(); }
  // compare-only batched pass: collect elements of sub-bin bin11
  {
    uint32_t i = (uint32_t)tid;
    while (i + 7u * NT < cnt) {
      uint32_t v[8];
#pragma unroll
      for (int k = 0; k < 8; k++) v[k] = L[i + (uint32_t)k * NT];
#pragma unroll
      for (int k = 0; k < 8; k++)
        if (((v[k] >> 6) & 2047u) == bin11) {
          uint32_t j = atomicAdd(&tcnt, 1u); if (j < 256u) tiny[j] = v[k];
        }
      i += 8u * NT;
    }
    for (; i < cnt; i += NT) {
      uint32_t v = L[i];
      if (((v >> 6) & 2047u) == bin11) {
        uint32_t j = atomicAdd(&tcnt, 1u); if (j < 256u) tiny[j] = v;
      }
    }
  }
  __syncthreads();
  uint32_t m = tcnt; if (m > 256u) m = 256u;
  for (uint32_t i = tid; i < m; i += NT) atomicAdd(&h64[tiny[i] & 63u], 1u);
  __syncthreads();
  if (tid < 2) bc[tid] = 0u;
  uint32_t local = (tid < 64) ? h64[tid] : 0u;
  uint32_t excl = scan_excl(local, wl);
  if (local > 0 && rk2 >= excl && rk2 < excl + local) bc[0] = (uint32_t)tid;
  __syncthreads();
  const uint32_t bin6 = bc[0];
  if (tid == 0)
    WS[bid == 0 ? W_VA : W_VB] = ((16384u + coarse) << 17) | (bin11 << 6) | bin6;
}

// kC: stream hist of |y - med| -> G2
__global__ __launch_bounds__(NT) void kC(const float* __restrict__ dren,
                                         uint32_t* __restrict__ WS, int P) {
  const int tid = threadIdx.x, bid = blockIdx.x, gid = bid * NT + tid;
  __shared__ uint32_t lh[8192];
  const float med = med_from(WS);
  for (int i = tid; i < 8192; i += NT) lh[i] = 0u;
  __syncthreads();
  const float4* d4 = (const float4*)dren;
  const int P4 = P >> 2;
  for (int i = gid; i < P4; i += GC * NT) {
    float4 d = d4[i];
    float dc[4] = { d.x, d.y, d.z, d.w };
#pragma unroll
    for (int k = 0; k < 4; k++) {
      float y; bool m;
      uint32_t w = m2w(yval_u(dc[k], y, m), med);
      uint32_t bin = (w >> 17) & 16383u;
      atomicAdd(&lh[bin >> 1], 1u << ((bin & 1u) << 4));
    }
  }
  for (int i = (P & ~3) + gid; i < P; i += GC * NT) {
    float y; bool m;
    uint32_t w = m2w(yval_u(dren[i], y, m), med);
    uint32_t bin = (w >> 17) & 16383u;
    atomicAdd(&lh[bin >> 1], 1u << ((bin & 1u) << 4));
  }
  __syncthreads();
  for (int w = tid; w < 8192; w += NT) {
    uint32_t pv = lh[w];
    if (pv) {
      uint32_t lo = pv & 0xFFFFu, hi = pv >> 16;
      if (lo) atomicAdd(&WS[W_G2 + 2 * w], lo);
      if (hi) atomicAdd(&WS[W_G2 + 2 * w + 1], hi);
    }
  }
}

// kD: redundant bins2 (-> W_SB2); collect lists2 + sub-hists -> W_H2A/W_H2B
__global__ __launch_bounds__(NT) void kD(const float* __restrict__ dren,
                                         uint32_t* __restrict__ WS, int P) {
  const int tid = threadIdx.x, bid = blockIdx.x, gid = bid * NT + tid;
  __shared__ uint32_t bufA[4096], bufB[4096];
  __shared__ uint32_t h2A[2048], h2B[2048];
  __shared__ uint32_t cA, cB, baseA, baseB;
  __shared__ uint32_t wl[4], bc4[4];
  const float med = med_from(WS);
  const uint32_t n = WS[W_N];
  const uint32_t nn = n ? n : 1u;
  g_select2(WS + W_G2, (nn - 1u) >> 1, nn >> 1, wl, bc4);
  const uint32_t binA2 = bc4[0], binB2 = bc4[2];
  const bool dv2 = (binA2 != binB2);
  if (tid == 0) {
    WS[W_SB2 + 0] = bc4[0]; WS[W_SB2 + 1] = bc4[1];
    WS[W_SB2 + 2] = bc4[2]; WS[W_SB2 + 3] = bc4[3];
    cA = 0; cB = 0;
  }
  for (int i = tid; i < 2048; i += NT) { h2A[i] = 0u; h2B[i] = 0u; }
  __syncthreads();
  const float4* d4 = (const float4*)dren;
  const int P4 = P >> 2;
  for (int i = gid; i < P4; i += GD * NT) {
    float4 d = d4[i];
    float dc[4] = { d.x, d.y, d.z, d.w };
#pragma unroll
    for (int k = 0; k < 4; k++) {
      float y; bool m;
      uint32_t w = m2w(yval_u(dc[k], y, m), med);
      uint32_t b = (w >> 17) & 16383u;
      if (b == binA2) {
        uint32_t j = atomicAdd(&cA, 1u); if (j < 4096u) bufA[j] = w;
        atomicAdd(&h2A[(w >> 6) & 2047u], 1u);
      } else if (dv2 && b == binB2) {
        uint32_t j = atomicAdd(&cB, 1u); if (j < 4096u) bufB[j] = w;
        atomicAdd(&h2B[(w >> 6) & 2047u], 1u);
      }
    }
  }
  for (int i = (P & ~3) + gid; i < P; i += GD * NT) {
    float y; bool m;
    uint32_t w = m2w(yval_u(dren[i], y, m), med);
    uint32_t b = (w >> 17) & 16383u;
    if (b == binA2) {
      uint32_t j = atomicAdd(&cA, 1u); if (j < 4096u) bufA[j] = w;
      atomicAdd(&h2A[(w >> 6) & 2047u], 1u);
    } else if (dv2 && b == binB2) {
      uint32_t j = atomicAdd(&cB, 1u); if (j < 4096u) bufB[j] = w;
      atomicAdd(&h2B[(w >> 6) & 2047u], 1u);
    }
  }
  __syncthreads();
  if (tid == 0) {
    uint32_t a = cA > 4096u ? 4096u : cA;
    uint32_t b = cB > 4096u ? 4096u : cB;
    cA = a; cB = b;
    baseA = a ? atomicAdd(&WS[W_CNT + 2], a) : 0u;
    baseB = b ? atomicAdd(&WS[W_CNT + 3], b) : 0u;
  }
  __syncthreads();
  for (uint32_t k = tid; k < cA; k += NT)
    if (baseA + k < LCAP) WS[W_LA2 + baseA + k] = bufA[k];
  for (uint32_t k = tid; k < cB; k += NT)
    if (baseB + k < LCAP) WS[W_LB2 + baseB + k] = bufB[k];
  for (int w = tid; w < 2048; w += NT) {
    uint32_t a = h2A[w]; if (a) atomicAdd(&WS[W_H2A + w], a);
    uint32_t b = h2B[w]; if (b) atomicAdd(&WS[W_H2B + w], b);
  }
}

// kDyn: 2 blocks; block b resolves rank b of median(|y-med|) -> W_WA / W_WB
__global__ __launch_bounds__(NT) void kDyn(uint32_t* __restrict__ WS) {
  const int tid = threadIdx.x, bid = blockIdx.x;
  __shared__ uint32_t tiny[256];
  __shared__ uint32_t h64[64];
  __shared__ uint32_t wl[4], bc[2];
  __shared__ uint32_t tcnt;
  const uint32_t binA2 = WS[W_SB2 + 0], rkA2 = WS[W_SB2 + 1];
  const uint32_t binB2 = WS[W_SB2 + 2], rkB2 = WS[W_SB2 + 3];
  const bool dv2 = (binA2 != binB2);
  uint32_t coarse, rk; const uint32_t *L, *H; uint32_t cnt;
  if (bid == 0) {
    coarse = binA2; rk = rkA2; L = WS + W_LA2; H = WS + W_H2A;
    cnt = WS[W_CNT + 2];
  } else {
    coarse = dv2 ? binB2 : binA2; rk = rkB2;
    L = dv2 ? (WS + W_LB2) : (WS + W_LA2);
    H = dv2 ? (WS + W_H2B) : (WS + W_H2A);
    cnt = dv2 ? WS[W_CNT + 3] : WS[W_CNT + 2];
  }
  if (cnt > LCAP) cnt = LCAP;
  h_select(H, rk, wl, bc);
  const uint32_t bin11 = bc[0], rk2 = bc[1];
  if (tid == 0) tcnt = 0u;
  if (tid < 64) h64[tid] = 0u;
  __syncthreads();
  {
    uint32_t i = (uint32_t)tid;
    while (i + 7u * NT < cnt) {
      uint32_t v[8];
#pragma unroll
      for (int k = 0; k < 8; k++) v[k] = L[i + (uint32_t)k * NT];
#pragma unroll
      for (int k = 0; k < 8; k++)
        if (((v[k] >> 6) & 2047u) == bin11) {
          uint32_t j = atomicAdd(&tcnt, 1u); if (j < 256u) tiny[j] = v[k];
        }
      i += 8u * NT;
    }
    for (; i < cnt; i += NT) {
      uint32_t v = L[i];
      if (((v >> 6) & 2047u) == bin11) {
        uint32_t j = atomicAdd(&tcnt, 1u); if (j < 256u) tiny[j] = v;
      }
    }
  }
  __syncthreads();
  uint32_t m = tcnt; if (m > 256u) m = 256u;
  for (uint32_t i = tid; i < m; i += NT) atomicAdd(&h64[tiny[i] & 63u], 1u);
  __syncthreads();
  if (tid < 2) bc[tid] = 0u;
  uint32_t local = (tid < 64) ? h64[tid] : 0u;
  uint32_t excl = scan_excl(local, wl);
  if (local > 0 && rk2 >= excl && rk2 < excl + local) bc[0] = (uint32_t)tid;
  __syncthreads();
  const uint32_t bin6 = bc[0];
  if (tid == 0)
    WS[bid == 0 ? W_WA : W_WB] = ((16384u + coarse) << 17) | (bin11 << 6) | bin6;
}

// kE: element-sliced scoring; each block owns ~196 (x,y) in LDS, each thread
// owns 4 candidates; counts accumulated via global atomicAdd (order-free ints)
__global__ __launch_bounds__(NT) void kE(uint32_t* __restrict__ WS) {
  const int tid = threadIdx.x, bid = blockIdx.x;
  __shared__ float lx[200], ly[200];
  float mad = __fmul_rn(__fadd_rn(u2f(WS[W_WA]), u2f(WS[W_WB])), 0.5f);
  float dyn = __fmul_rn(mad, 0.5f);
  if (dyn < 1e-5f) dyn = 0.01f;   // THRESH
  const int e0 = (bid * 50000) / GE, e1 = ((bid + 1) * 50000) / GE;
  const int cnt = e1 - e0;
  const float* x_sub = (const float*)WS + W_XSUB;
  const float* y_sub = (const float*)WS + W_YSUB;
  if (tid < cnt) { lx[tid] = x_sub[e0 + tid]; ly[tid] = y_sub[e0 + tid]; }
  __syncthreads();
  const float* scales = (const float*)WS + W_SCALES;
  const float* shifts = (const float*)WS + W_SHIFTS;
  float ss[4], tt[4]; int c[4];
#pragma unroll
  for (int j = 0; j < 4; j++) {
    int cand = tid + 256 * j;
    ss[j] = (cand < 1000) ? scales[cand] : 0.0f;
    tt[j] = (cand < 1000) ? shifts[cand] : 0.0f;
    c[j] = 0;
  }
  for (int e = 0; e < cnt; e++) {
    float xe = lx[e], ye = ly[e];   // LDS broadcast: conflict-free
#pragma unroll
    for (int j = 0; j < 4; j++) {
      float r = fabsf(__fsub_rn(__fadd_rn(__fmul_rn(ss[j], xe), tt[j]), ye));
      c[j] += (r < dyn) ? 1 : 0;
    }
  }
  int* counts = (int*)WS + W_COUNTS;
#pragma unroll
  for (int j = 0; j < 4; j++) {
    int cand = tid + 256 * j;
    if (cand < 1000 && c[j] > 0) atomicAdd(&counts[cand], c[j]);
  }
}

// kF: redundant argmax -> s,t; final elemwise; per-block loss atomicAdd
__global__ __launch_bounds__(NT) void kF(const float* __restrict__ dren,
                                         const float* __restrict__ dpri,
                                         float* __restrict__ out,
                                         uint32_t* __restrict__ WS, int P) {
  const int tid = threadIdx.x, bid = blockIdx.x, gid = bid * NT + tid;
  const int lane = tid & 63, wid = tid >> 6;
  __shared__ int ired[4], iidx[4];
  __shared__ float fbcast[2];
  __shared__ double dred[4];
  {
    const int* counts = (const int*)WS + W_COUNTS;
    const float* scales = (const float*)WS + W_SCALES;
    const float* shifts = (const float*)WS + W_SHIFTS;
    int bcn = -2, bix = 0x7FFFFFFF;
    for (int j = tid; j < 1000; j += NT) {
      int cc = counts[j];
      if (!(scales[j] > 0.0f)) cc = -1;
      if (cc > bcn) { bcn = cc; bix = j; }
    }
    for (int off = 32; off > 0; off >>= 1) {
      int oc = __shfl_down(bcn, off), oi = __shfl_down(bix, off);
      if (oc > bcn || (oc == bcn && oi < bix)) { bcn = oc; bix = oi; }
    }
    if (lane == 0) { ired[wid] = bcn; iidx[wid] = bix; }
    __syncthreads();
    if (tid == 0) {
      for (int w = 1; w < 4; w++) {
        if (ired[w] > ired[0] || (ired[w] == ired[0] && iidx[w] < iidx[0])) {
          ired[0] = ired[w]; iidx[0] = iidx[w];
        }
      }
      bool valid = ired[0] >= 0;
      float s = valid ? scales[iidx[0]] : 1.0f;
      float t = valid ? shifts[iidx[0]] : 0.0f;
      uint32_t n = WS[W_N];
      if (n < 10u) { s = 1.0f; t = 0.0f; }
      fbcast[0] = s; fbcast[1] = t;
    }
    __syncthreads();
  }
  const float s = fbcast[0], t = fbcast[1];
  float* out_y = out + 1;
  float* out_depth = out + 1 + P;
  double acc = 0.0;
  const float4* d4 = (const float4*)dren;
  const float4* p4 = (const float4*)dpri;
  const int P4 = P >> 2;
  for (int i = gid; i < P4; i += GF * NT) {
    float4 d = d4[i], p = p4[i];
    float dc[4] = { d.x, d.y, d.z, d.w };
    float pc[4] = { p.x, p.y, p.z, p.w };
#pragma unroll
    for (int k = 0; k < 4; k++) {
      float yv = __fdiv_rn(1.0f, __fadd_rn(dc[k], 1e-6f));
      out_y[4 * i + k] = yv;
      float al = __fadd_rn(__fmul_rn(s, pc[k]), t);
      out_depth[4 * i + k] = __fdiv_rn(1.0f, fmaxf(al, 1e-4f));
      bool m = (dc[k] > 0.1f) && (dc[k] < 100.0f) && isfinite(dc[k]);
      if (m) acc += (double)fabsf(__fsub_rn(al, yv));
    }
  }
  for (int i = (P & ~3) + gid; i < P; i += GF * NT) {
    float dv = dren[i];
    float yv = __fdiv_rn(1.0f, __fadd_rn(dv, 1e-6f));
    out_y[i] = yv;
    float al = __fadd_rn(__fmul_rn(s, dpri[i]), t);
    out_depth[i] = __fdiv_rn(1.0f, fmaxf(al, 1e-4f));
    bool m = (dv > 0.1f) && (dv < 100.0f) && isfinite(dv);
    if (m) acc += (double)fabsf(__fsub_rn(al, yv));
  }
  for (int off = 32; off > 0; off >>= 1) acc += __shfl_down(acc, off);
  __syncthreads();
  if (lane == 0) dred[wid] = acc;
  __syncthreads();
  if (tid == 0)
    atomicAdd((double*)(WS + W_LOSS), dred[0] + dred[1] + dred[2] + dred[3]);
}

// kG: final loss scalar
__global__ void kG(const uint32_t* __restrict__ WS, float* __restrict__ out) {
  if (threadIdx.x == 0 && blockIdx.x == 0) {
    double total = *((const double*)(WS + W_LOSS));
    uint32_t n = WS[W_N];
    uint32_t nd = n ? n : 1u;
    float l1 = __fdiv_rn((float)total, (float)nd);
    out[0] = (n < 100u) ? 0.0f : __fmul_rn(0.5f, l1);
  }
}

// ---------------------------------------------------------------------------
extern "C" void kernel_launch(void* const* d_in, const int* in_sizes, int n_in,
                              void* d_out, int out_size, void* d_ws, size_t ws_size,
                              hipStream_t stream) {
  const float* d_ren = (const float*)d_in[0];
  const float* d_pri = (const float*)d_in[1];
  float* out = (float*)d_out;
  uint32_t* WS = (uint32_t*)d_ws;
  int P = in_sizes[0];

  k_zero<<<(W_ZEND + NT - 1) / NT, NT, 0, stream>>>(WS);
  kA<<<GA, NT, 0, stream>>>(d_ren, WS, P);
  kB<<<GB, NT, 0, stream>>>(d_ren, d_pri, WS, P);
  kMed<<<2, NT, 0, stream>>>(WS);
  kC<<<GC, NT, 0, stream>>>(d_ren, WS, P);
  kD<<<GD, NT, 0, stream>>>(d_ren, WS, P);
  kDyn<<<2, NT, 0, stream>>>(WS);
  kE<<<GE, NT, 0, stream>>>(WS);
  kF<<<GF, NT, 0, stream>>>(d_ren, d_pri, out, WS, P);
  kG<<<1, 64, 0, stream>>>(WS, out);
}